// Round 5
// baseline (115.962 us; speedup 1.0000x reference)
//
#include <hip/hip_runtime.h>
#include <math.h>

// B=4096, K=128, D=256.
// out[b,d] = sqrt(1-e) * sum_k p_k * (x - a*c)/var,  var = 1 + e*(s^2-1)
// lp_k = -0.5*S1 - 128*ln2*S2 + ln w_k  (k-uniform const dropped)
//   S1 = sum_d diff^2/var, S2 = sum_d log2(var)
//
// Evidence through R4: VALU-issue time is conserved (~26 us); duty cycle
// tracks INDEPENDENT BLOCKS PER CU (4 blocks -> 53-56%, 2 -> 40%), not
// waves (R1) and not prefetch depth (R4).  The duty holes are the
// block-synchronous barrier/softmax phases; only phase-staggered sibling
// blocks fill them.  R0/R1 were grid-capped at 4 blocks/CU.
// This revision: G=2 at 256 threads -> 2048 blocks = 8 blocks/CU.
// Per-element math bit-identical to R0 (p-pair loop collapses to one f2).

constexpr int Kc = 128;
constexpr int Dc = 256;
constexpr int G  = 2;   // batch rows per block (1 f2 pair)

typedef float f2 __attribute__((ext_vector_type(2)));
typedef float f4 __attribute__((ext_vector_type(4)));

static __device__ __forceinline__ f2 fma2(f2 a, f2 b, f2 c) {
    return __builtin_elementwise_fma(a, b, c);
}
static __device__ __forceinline__ f2 splat2(float s) { return (f2){s, s}; }

// prep: CA8[(d>>2)][k][8] = {c0,c1,c2,c3,A0,A1,A2,A3} (pass-1, transposed);
//       P2[k*Dc+d] = {c, A} (pass-2), A = s^2-1.
__global__ void prep_kernel(const float* __restrict__ centers,
                            const float* __restrict__ stds,
                            float* __restrict__ CA8, f2* __restrict__ P2) {
    int idx = blockIdx.x * blockDim.x + threadIdx.x;   // k*Dc + d, read-coalesced
    if (idx >= Kc * Dc) return;
    int k = idx >> 8;
    int d = idx & (Dc - 1);
    float c = centers[idx];
    float s = stds[idx];
    float A = s * s - 1.0f;
    int o = (d >> 2) * (Kc * 8) + k * 8 + (d & 3);
    CA8[o]     = c;
    CA8[o + 4] = A;
    P2[idx] = (f2){c, A};
}

__global__ __launch_bounds__(256, 8) void score_kernel(
    const float* __restrict__ x, const float* __restrict__ t,
    const float* __restrict__ weights,
    const float* __restrict__ CA8, const f2* __restrict__ P2,
    float* __restrict__ out)
{
    const int b0  = blockIdx.x * G;
    const int tid = threadIdx.x;

    __shared__ __align__(16) f2 xT2[Dc];        // x for the 2 rows, packed
    __shared__ float part1[G][2][Kc];
    __shared__ float partL[G][2][Kc];
    __shared__ __align__(16) f2 peT2[Kc];       // unnormalized softmax numerators
    __shared__ float wmax[G][2];
    __shared__ float wsum[G][2];

    // per-row scalars
    float e[G], na[G], sg[G];
    #pragma unroll
    for (int g = 0; g < G; ++g) {
        float tt = t[b0 + g];
        float Bt = fmaf(9.95f * tt, tt, 0.1f * tt);
        float ee = __expf(-Bt);
        e[g]  = ee;
        na[g] = -sqrtf(ee);
        sg[g] = sqrtf(1.0f - ee);
    }
    f2 e2  = {e[0], e[1]};
    f2 na2 = {na[0], na[1]};
    const f2 one2 = {1.0f, 1.0f};

    xT2[tid] = (f2){x[b0 * Dc + tid], x[(b0 + 1) * Dc + tid]};
    __syncthreads();

    // ---------------- pass 1: thread = (k, half-of-D) ----------------
    const int kk    = tid & (Kc - 1);
    const int half  = tid >> 7;
    const int dbase = half * (Dc / 2);           // 128 d's per thread -> 8 grps

    f2 acc1 = {0.f, 0.f};
    float accL[G] = {0.f, 0.f};

    for (int grp = 0; grp < 8; ++grp) {
        f2 prod = {1.f, 1.f};
        #pragma unroll
        for (int q = 0; q < 4; ++q) {
            const int d0 = dbase + (grp * 4 + q) * 4;
            const float* base = CA8 + ((size_t)(d0 >> 2) * Kc + kk) * 8;
            f4 c4 = *(const f4*)base;          // dwordx4, coalesced over kk
            f4 A4 = *(const f4*)(base + 4);    // same addr + imm 16
            f2 x0 = xT2[d0 + 0];               // LDS b64 broadcast (d uniform)
            f2 x1 = xT2[d0 + 1];
            f2 x2 = xT2[d0 + 2];
            f2 x3 = xT2[d0 + 3];
            f2 v0 = fma2(e2, splat2(A4[0]), one2);   // var in [0.25,1]
            f2 v1 = fma2(e2, splat2(A4[1]), one2);
            f2 v2 = fma2(e2, splat2(A4[2]), one2);
            f2 v3 = fma2(e2, splat2(A4[3]), one2);
            f2 f0 = fma2(na2, splat2(c4[0]), x0);
            f2 f1 = fma2(na2, splat2(c4[1]), x1);
            f2 f2_ = fma2(na2, splat2(c4[2]), x2);
            f2 f3 = fma2(na2, splat2(c4[3]), x3);
            f2 s0 = f0 * f0, s1 = f1 * f1, s2 = f2_ * f2_, s3 = f3 * f3;
            f2 d01 = v0 * v1, d23 = v2 * v3;
            f2 n01 = fma2(s1, v0, s0 * v1);
            f2 n23 = fma2(s3, v2, s2 * v3);
            f2 den = d01 * d23;                      // >= 0.25^4
            f2 num = fma2(n23, d01, n01 * d23);
            f2 r = {__builtin_amdgcn_rcpf(den[0]),
                    __builtin_amdgcn_rcpf(den[1])};
            acc1 = fma2(num, r, acc1);
            prod = prod * den;
        }
        accL[0] += __log2f(prod[0]);           // 1 log per 16 d per g
        accL[1] += __log2f(prod[1]);
    }
    part1[0][half][kk] = acc1[0];
    part1[1][half][kk] = acc1[1];
    partL[0][half][kk] = accL[0];
    partL[1][half][kk] = accL[1];
    __syncthreads();

    // ---------------- softmax over k (threads < K, 2 full waves) ----------------
    float lpv[G];
    if (tid < Kc) {
        float lw = __logf(weights[tid]);
        #pragma unroll
        for (int g = 0; g < G; ++g) {
            float S1 = part1[g][0][tid] + part1[g][1][tid];
            float S2 = partL[g][0][tid] + partL[g][1][tid];
            lpv[g] = fmaf(-0.5f, S1, fmaf(-88.72283911167299f, S2, lw)); // 128*ln2
            float m = lpv[g];
            #pragma unroll
            for (int off = 32; off > 0; off >>= 1)
                m = fmaxf(m, __shfl_xor(m, off, 64));
            if ((tid & 63) == 0) wmax[g][tid >> 6] = m;
        }
    }
    __syncthreads();
    if (tid < Kc) {
        float pe[G];
        #pragma unroll
        for (int g = 0; g < G; ++g) {
            float m  = fmaxf(wmax[g][0], wmax[g][1]);
            pe[g] = __expf(lpv[g] - m);
            float s = pe[g];
            #pragma unroll
            for (int off = 32; off > 0; off >>= 1)
                s += __shfl_xor(s, off, 64);
            if ((tid & 63) == 0) wsum[g][tid >> 6] = s;
        }
        peT2[tid] = (f2){pe[0], pe[1]};        // unnormalized; 1/Z in epilogue
    }
    __syncthreads();

    // ---------------- pass 2: thread = d ----------------
    f2 xp = xT2[tid];
    f2 O = {0.f, 0.f};
    const f2* pp = P2 + tid;

    for (int kq = 0; kq < 32; ++kq) {
        const int k0 = kq * 4;
        f2 ca0 = pp[(k0 + 0) * Dc];            // dwordx2 {c,A}, coalesced
        f2 ca1 = pp[(k0 + 1) * Dc];
        f2 ca2 = pp[(k0 + 2) * Dc];
        f2 ca3 = pp[(k0 + 3) * Dc];
        f2 p0 = peT2[k0 + 0];                  // LDS b64 broadcast
        f2 p1 = peT2[k0 + 1];
        f2 p2 = peT2[k0 + 2];
        f2 p3 = peT2[k0 + 3];
        f2 v0 = fma2(e2, splat2(ca0[1]), one2);
        f2 v1 = fma2(e2, splat2(ca1[1]), one2);
        f2 v2 = fma2(e2, splat2(ca2[1]), one2);
        f2 v3 = fma2(e2, splat2(ca3[1]), one2);
        f2 f0 = fma2(na2, splat2(ca0[0]), xp);
        f2 f1 = fma2(na2, splat2(ca1[0]), xp);
        f2 f2_ = fma2(na2, splat2(ca2[0]), xp);
        f2 f3 = fma2(na2, splat2(ca3[0]), xp);
        f2 u0 = p0 * f0;
        f2 u1 = p1 * f1;
        f2 u2 = p2 * f2_;
        f2 u3 = p3 * f3;
        f2 d01 = v0 * v1, d23 = v2 * v3;
        f2 n01 = fma2(u1, v0, u0 * v1);
        f2 n23 = fma2(u3, v2, u2 * v3);
        f2 den = d01 * d23;
        f2 num = fma2(n23, d01, n01 * d23);
        f2 r = {__builtin_amdgcn_rcpf(den[0]),
                __builtin_amdgcn_rcpf(den[1])};
        O = fma2(num, r, O);
    }

    #pragma unroll
    for (int g = 0; g < G; ++g) {
        float Z = wsum[g][0] + wsum[g][1];
        out[(b0 + g) * Dc + tid] = sg[g] * __builtin_amdgcn_rcpf(Z) * O[g];
    }
}

extern "C" void kernel_launch(void* const* d_in, const int* in_sizes, int n_in,
                              void* d_out, int out_size, void* d_ws, size_t ws_size,
                              hipStream_t stream) {
    const float* x       = (const float*)d_in[0];
    const float* t       = (const float*)d_in[1];
    const float* centers = (const float*)d_in[2];
    const float* stds    = (const float*)d_in[3];
    const float* weights = (const float*)d_in[4];
    float* outp = (float*)d_out;

    float* CA8 = (float*)d_ws;                    // [D/4][K][8]  (256 KB)
    f2*    P2  = (f2*)(CA8 + Kc * Dc * 2);        // [K][D] {c,A} (256 KB)

    const int B = in_sizes[1];                    // 4096

    prep_kernel<<<(Kc * Dc + 255) / 256, 256, 0, stream>>>(centers, stds, CA8, P2);
    score_kernel<<<B / G, 256, 0, stream>>>(x, t, weights, CA8, P2, outp);
}

// Round 6
// 105.530 us; speedup vs baseline: 1.0989x; 1.0989x over previous
//
#include <hip/hip_runtime.h>
#include <math.h>

// B=4096, K=128, D=256.
// out[b,d] = sqrt(1-e) * sum_k p_k * (x - a*c)/var,  var = 1 + e*(s^2-1)
// lp_k = -0.5*S1 - 128*ln2*S2 + ln w_k  (k-uniform const dropped)
//   S1 = sum_d diff^2/var, S2 = sum_d log2(var)
//
// R0-R5 lesson: duration tracks TOTAL INSTRUCTION WORK (VALU pk-ops +
// quarter-rate transcendentals), not occupancy/latency/traffic.  This
// revision cuts work on the proven R0 config (G=4, 256 thr, 1024 blocks):
//  1. pass 1: 8-way rcp combining (one rcp per 8 d's instead of 4) —
//     +1 pk-op, -2 scalar rcp per 8d.  den8 >= 0.25^8 = 1.5e-5, safe.
//  2. pass 2: softmax sparsity.  pe=exp(lp-m)<=1 and lp spread is huge,
//     so almost all of the 32 k-quads have max(pe) < 1e-6.  One wave
//     ballots/compacts the active quads after softmax; pass 2 iterates
//     only those (block-uniform branch, P2 loads skipped too).
//     Error bound: 127 * 1e-6 * |f/var|max ~ 3e-3 << 0.117 threshold.

constexpr int Kc = 128;
constexpr int Dc = 256;
constexpr int G  = 4;   // batch rows per block (2 f2 pairs)

typedef float f2 __attribute__((ext_vector_type(2)));
typedef float f4 __attribute__((ext_vector_type(4)));

static __device__ __forceinline__ f2 fma2(f2 a, f2 b, f2 c) {
    return __builtin_elementwise_fma(a, b, c);
}
static __device__ __forceinline__ f2 splat2(float s) { return (f2){s, s}; }

// prep: CA8[(d>>2)][k][8] = {c0,c1,c2,c3,A0,A1,A2,A3} (pass-1, transposed);
//       P2[k*Dc+d] = {c, A} (pass-2), A = s^2-1.
__global__ void prep_kernel(const float* __restrict__ centers,
                            const float* __restrict__ stds,
                            float* __restrict__ CA8, f2* __restrict__ P2) {
    int idx = blockIdx.x * blockDim.x + threadIdx.x;   // k*Dc + d, read-coalesced
    if (idx >= Kc * Dc) return;
    int k = idx >> 8;
    int d = idx & (Dc - 1);
    float c = centers[idx];
    float s = stds[idx];
    float A = s * s - 1.0f;
    int o = (d >> 2) * (Kc * 8) + k * 8 + (d & 3);
    CA8[o]     = c;
    CA8[o + 4] = A;
    P2[idx] = (f2){c, A};
}

__global__ __launch_bounds__(256, 4) void score_kernel(
    const float* __restrict__ x, const float* __restrict__ t,
    const float* __restrict__ weights,
    const float* __restrict__ CA8, const f2* __restrict__ P2,
    float* __restrict__ out)
{
    const int b0  = blockIdx.x * G;
    const int tid = threadIdx.x;

    __shared__ __align__(16) float xT[Dc][G];   // x transposed
    __shared__ float part1[G][2][Kc];
    __shared__ float partL[G][2][Kc];
    __shared__ __align__(16) float peT[Kc][G];  // unnormalized softmax numerators
    __shared__ float wmax[G][2];
    __shared__ float wsum[G][2];
    __shared__ int   activeList[32];            // compacted k-quads
    __shared__ int   activeCnt;

    // per-row scalars
    float e[G], na[G], sg[G];
    #pragma unroll
    for (int g = 0; g < G; ++g) {
        float tt = t[b0 + g];
        float Bt = fmaf(9.95f * tt, tt, 0.1f * tt);
        float ee = __expf(-Bt);
        e[g]  = ee;
        na[g] = -sqrtf(ee);
        sg[g] = sqrtf(1.0f - ee);
    }
    f2 e2[2]  = {{e[0], e[1]}, {e[2], e[3]}};
    f2 na2[2] = {{na[0], na[1]}, {na[2], na[3]}};
    const f2 one2 = {1.0f, 1.0f};

    #pragma unroll
    for (int g = 0; g < G; ++g)
        xT[tid][g] = x[(b0 + g) * Dc + tid];
    __syncthreads();

    // ---------------- pass 1: thread = (k, half-of-D) ----------------
    const int kk    = tid & (Kc - 1);
    const int half  = tid >> 7;
    const int dbase = half * (Dc / 2);           // 128 d's per thread

    const f4* xTv = (const f4*)(&xT[0][0]);

    f2 acc1[2] = {{0.f, 0.f}, {0.f, 0.f}};
    float accL[G] = {0.f, 0.f, 0.f, 0.f};

    for (int grp = 0; grp < 8; ++grp) {          // 16 d's per grp
        f2 prod[2] = {{1.f, 1.f}, {1.f, 1.f}};
        #pragma unroll
        for (int qp = 0; qp < 2; ++qp) {         // 8 d's per qp
            const int d0 = dbase + grp * 16 + qp * 8;
            const float* baseA = CA8 + ((size_t)(d0 >> 2) * Kc + kk) * 8;
            const float* baseB = baseA + Kc * 8;
            f4 c4a = *(const f4*)baseA;          // dwordx4, coalesced over kk
            f4 A4a = *(const f4*)(baseA + 4);
            f4 c4b = *(const f4*)baseB;
            f4 A4b = *(const f4*)(baseB + 4);
            f4 xv0 = xTv[d0 + 0];                // LDS b128 broadcast (d uniform)
            f4 xv1 = xTv[d0 + 1];
            f4 xv2 = xTv[d0 + 2];
            f4 xv3 = xTv[d0 + 3];
            f4 xv4 = xTv[d0 + 4];
            f4 xv5 = xTv[d0 + 5];
            f4 xv6 = xTv[d0 + 6];
            f4 xv7 = xTv[d0 + 7];
            #pragma unroll
            for (int p = 0; p < 2; ++p) {
                f2 ep = e2[p], nap = na2[p];
                // sub-tree A: d0..d0+3
                f2 vA0 = fma2(ep, splat2(A4a[0]), one2);  // var in [0.25,1]
                f2 vA1 = fma2(ep, splat2(A4a[1]), one2);
                f2 vA2 = fma2(ep, splat2(A4a[2]), one2);
                f2 vA3 = fma2(ep, splat2(A4a[3]), one2);
                f2 fA0 = fma2(nap, splat2(c4a[0]), (f2){xv0[2*p], xv0[2*p+1]});
                f2 fA1 = fma2(nap, splat2(c4a[1]), (f2){xv1[2*p], xv1[2*p+1]});
                f2 fA2 = fma2(nap, splat2(c4a[2]), (f2){xv2[2*p], xv2[2*p+1]});
                f2 fA3 = fma2(nap, splat2(c4a[3]), (f2){xv3[2*p], xv3[2*p+1]});
                f2 sA0 = fA0 * fA0, sA1 = fA1 * fA1;
                f2 sA2 = fA2 * fA2, sA3 = fA3 * fA3;
                f2 dA01 = vA0 * vA1, dA23 = vA2 * vA3;
                f2 nA01 = fma2(sA1, vA0, sA0 * vA1);
                f2 nA23 = fma2(sA3, vA2, sA2 * vA3);
                f2 denA = dA01 * dA23;
                f2 numA = fma2(nA23, dA01, nA01 * dA23);
                // sub-tree B: d0+4..d0+7
                f2 vB0 = fma2(ep, splat2(A4b[0]), one2);
                f2 vB1 = fma2(ep, splat2(A4b[1]), one2);
                f2 vB2 = fma2(ep, splat2(A4b[2]), one2);
                f2 vB3 = fma2(ep, splat2(A4b[3]), one2);
                f2 fB0 = fma2(nap, splat2(c4b[0]), (f2){xv4[2*p], xv4[2*p+1]});
                f2 fB1 = fma2(nap, splat2(c4b[1]), (f2){xv5[2*p], xv5[2*p+1]});
                f2 fB2 = fma2(nap, splat2(c4b[2]), (f2){xv6[2*p], xv6[2*p+1]});
                f2 fB3 = fma2(nap, splat2(c4b[3]), (f2){xv7[2*p], xv7[2*p+1]});
                f2 sB0 = fB0 * fB0, sB1 = fB1 * fB1;
                f2 sB2 = fB2 * fB2, sB3 = fB3 * fB3;
                f2 dB01 = vB0 * vB1, dB23 = vB2 * vB3;
                f2 nB01 = fma2(sB1, vB0, sB0 * vB1);
                f2 nB23 = fma2(sB3, vB2, sB2 * vB3);
                f2 denB = dB01 * dB23;
                f2 numB = fma2(nB23, dB01, nB01 * dB23);
                // 8-way combine: one rcp per 8 d's
                f2 den8 = denA * denB;                   // >= 0.25^8
                f2 num8 = fma2(numB, denA, numA * denB);
                f2 r = {__builtin_amdgcn_rcpf(den8[0]),
                        __builtin_amdgcn_rcpf(den8[1])};
                acc1[p] = fma2(num8, r, acc1[p]);
                prod[p] = prod[p] * den8;
            }
        }
        accL[0] += __log2f(prod[0][0]);        // 1 log per 16 d per g
        accL[1] += __log2f(prod[0][1]);
        accL[2] += __log2f(prod[1][0]);
        accL[3] += __log2f(prod[1][1]);
    }
    #pragma unroll
    for (int p = 0; p < 2; ++p) {
        part1[2*p  ][half][kk] = acc1[p][0];
        part1[2*p+1][half][kk] = acc1[p][1];
    }
    #pragma unroll
    for (int g = 0; g < G; ++g)
        partL[g][half][kk] = accL[g];
    __syncthreads();

    // ---------------- softmax over k (threads < K, 2 full waves) ----------------
    float lpv[G];
    if (tid < Kc) {
        float lw = __logf(weights[tid]);
        #pragma unroll
        for (int g = 0; g < G; ++g) {
            float S1 = part1[g][0][tid] + part1[g][1][tid];
            float S2 = partL[g][0][tid] + partL[g][1][tid];
            lpv[g] = fmaf(-0.5f, S1, fmaf(-88.72283911167299f, S2, lw)); // 128*ln2
            float m = lpv[g];
            #pragma unroll
            for (int off = 32; off > 0; off >>= 1)
                m = fmaxf(m, __shfl_xor(m, off, 64));
            if ((tid & 63) == 0) wmax[g][tid >> 6] = m;
        }
    }
    __syncthreads();
    if (tid < Kc) {
        #pragma unroll
        for (int g = 0; g < G; ++g) {
            float m  = fmaxf(wmax[g][0], wmax[g][1]);
            float pe = __expf(lpv[g] - m);
            peT[tid][g] = pe;                  // unnormalized; 1/Z in epilogue
            float s = pe;
            #pragma unroll
            for (int off = 32; off > 0; off >>= 1)
                s += __shfl_xor(s, off, 64);
            if ((tid & 63) == 0) wsum[g][tid >> 6] = s;
        }
    }
    __syncthreads();

    // ------- compact the active k-quads (softmax sparsity), one wave -------
    const f4* peTv = (const f4*)(&peT[0][0]);
    if (tid < 32) {
        const int k0 = tid * 4;
        f4 q0 = peTv[k0 + 0];
        f4 q1 = peTv[k0 + 1];
        f4 q2 = peTv[k0 + 2];
        f4 q3 = peTv[k0 + 3];
        float m0 = fmaxf(fmaxf(q0[0], q0[1]), fmaxf(q0[2], q0[3]));
        float m1 = fmaxf(fmaxf(q1[0], q1[1]), fmaxf(q1[2], q1[3]));
        float m2 = fmaxf(fmaxf(q2[0], q2[1]), fmaxf(q2[2], q2[3]));
        float m3 = fmaxf(fmaxf(q3[0], q3[1]), fmaxf(q3[2], q3[3]));
        float mx = fmaxf(fmaxf(m0, m1), fmaxf(m2, m3));
        bool act = mx >= 1e-6f;                // pe<=1; skipped mass < 1e-6 each
        unsigned long long mask = __ballot(act);
        int pos = __popcll(mask & ((1ULL << tid) - 1ULL));
        if (act) activeList[pos] = tid;
        if (tid == 0) activeCnt = (int)__popcll(mask);
    }
    __syncthreads();

    // ---------------- pass 2: thread = d, active k-quads only ----------------
    f4 xvv = xTv[tid];
    f2 xp[2] = {{xvv[0], xvv[1]}, {xvv[2], xvv[3]}};
    f2 O[2] = {{0.f, 0.f}, {0.f, 0.f}};
    const f2* pp = P2 + tid;
    const int M = activeCnt;

    for (int i = 0; i < M; ++i) {
        const int k0 = activeList[i] * 4;
        f2 ca0 = pp[(k0 + 0) * Dc];            // dwordx2 {c,A}, coalesced
        f2 ca1 = pp[(k0 + 1) * Dc];
        f2 ca2 = pp[(k0 + 2) * Dc];
        f2 ca3 = pp[(k0 + 3) * Dc];
        f4 p0 = peTv[k0 + 0];                  // LDS b128 broadcast
        f4 p1 = peTv[k0 + 1];
        f4 p2 = peTv[k0 + 2];
        f4 p3 = peTv[k0 + 3];
        #pragma unroll
        for (int p = 0; p < 2; ++p) {
            f2 ep = e2[p], nap = na2[p];
            f2 v0 = fma2(ep, splat2(ca0[1]), one2);
            f2 v1 = fma2(ep, splat2(ca1[1]), one2);
            f2 v2 = fma2(ep, splat2(ca2[1]), one2);
            f2 v3 = fma2(ep, splat2(ca3[1]), one2);
            f2 f0 = fma2(nap, splat2(ca0[0]), xp[p]);
            f2 f1 = fma2(nap, splat2(ca1[0]), xp[p]);
            f2 f2_ = fma2(nap, splat2(ca2[0]), xp[p]);
            f2 f3 = fma2(nap, splat2(ca3[0]), xp[p]);
            f2 u0 = (f2){p0[2*p], p0[2*p+1]} * f0;
            f2 u1 = (f2){p1[2*p], p1[2*p+1]} * f1;
            f2 u2 = (f2){p2[2*p], p2[2*p+1]} * f2_;
            f2 u3 = (f2){p3[2*p], p3[2*p+1]} * f3;
            f2 d01 = v0 * v1, d23 = v2 * v3;
            f2 n01 = fma2(u1, v0, u0 * v1);
            f2 n23 = fma2(u3, v2, u2 * v3);
            f2 den = d01 * d23;
            f2 num = fma2(n23, d01, n01 * d23);
            f2 r = {__builtin_amdgcn_rcpf(den[0]),
                    __builtin_amdgcn_rcpf(den[1])};
            O[p] = fma2(num, r, O[p]);
        }
    }

    #pragma unroll
    for (int p = 0; p < 2; ++p) {
        #pragma unroll
        for (int j = 0; j < 2; ++j) {
            int g = 2 * p + j;
            float Z = wsum[g][0] + wsum[g][1];
            out[(b0 + g) * Dc + tid] = sg[g] * __builtin_amdgcn_rcpf(Z) * O[p][j];
        }
    }
}

extern "C" void kernel_launch(void* const* d_in, const int* in_sizes, int n_in,
                              void* d_out, int out_size, void* d_ws, size_t ws_size,
                              hipStream_t stream) {
    const float* x       = (const float*)d_in[0];
    const float* t       = (const float*)d_in[1];
    const float* centers = (const float*)d_in[2];
    const float* stds    = (const float*)d_in[3];
    const float* weights = (const float*)d_in[4];
    float* outp = (float*)d_out;

    float* CA8 = (float*)d_ws;                    // [D/4][K][8]  (256 KB)
    f2*    P2  = (f2*)(CA8 + Kc * Dc * 2);        // [K][D] {c,A} (256 KB)

    const int B = in_sizes[1];                    // 4096

    prep_kernel<<<(Kc * Dc + 255) / 256, 256, 0, stream>>>(centers, stds, CA8, P2);
    score_kernel<<<B / G, 256, 0, stream>>>(x, t, weights, CA8, P2, outp);
}

// Round 7
// 105.428 us; speedup vs baseline: 1.0999x; 1.0010x over previous
//
#include <hip/hip_runtime.h>
#include <math.h>

// B=4096, K=128, D=256.
// out[b,d] = sqrt(1-e) * sum_k p_k * (x - a*c)/var,  var = 1 + e*(s^2-1)
// lp_k = -0.5*S1 - 128*ln2*S2 + ln w_k  (k-uniform const dropped)
//   S1 = sum_d diff^2/var, S2 = sum_d log2(var)
//
// R0-R6 conclusion: the kernel is VALU-EXECUTION-bound (R0 measured 48.4us
// vs 44.6us pure-execution model = 92%).  Only instruction-count cuts win.
// R7: 16-way reciprocal combining in BOTH passes via sequential num/den
// merging (N' = N*d + n*D; D' = D*d, 3 ops/merge).  One rcp per 16 d's
// (pass 1) / 16 k's (pass 2).  The grp denominator product IS the log2
// argument (free S2).  den16 >= 0.25^16 = 2.3e-10: normal, safe.
// Sparsity (R6) reverted: softmax is dense for high-t rows (a->0, var->1
// makes components indistinguishable), so the skip rarely fires.
// Model: 7.0->6.4 cy/elem (pass1), 6.5->6.1 (pass2) => ~44.5us.

constexpr int Kc = 128;
constexpr int Dc = 256;
constexpr int G  = 4;   // batch rows per block (2 f2 pairs)

typedef float f2 __attribute__((ext_vector_type(2)));
typedef float f4 __attribute__((ext_vector_type(4)));

static __device__ __forceinline__ f2 fma2(f2 a, f2 b, f2 c) {
    return __builtin_elementwise_fma(a, b, c);
}
static __device__ __forceinline__ f2 splat2(float s) { return (f2){s, s}; }

// prep: CA8[(d>>2)][k][8] = {c0,c1,c2,c3,A0,A1,A2,A3} (pass-1, transposed);
//       P2[k*Dc+d] = {c, A} (pass-2), A = s^2-1.
__global__ void prep_kernel(const float* __restrict__ centers,
                            const float* __restrict__ stds,
                            float* __restrict__ CA8, f2* __restrict__ P2) {
    int idx = blockIdx.x * blockDim.x + threadIdx.x;   // k*Dc + d, read-coalesced
    if (idx >= Kc * Dc) return;
    int k = idx >> 8;
    int d = idx & (Dc - 1);
    float c = centers[idx];
    float s = stds[idx];
    float A = s * s - 1.0f;
    int o = (d >> 2) * (Kc * 8) + k * 8 + (d & 3);
    CA8[o]     = c;
    CA8[o + 4] = A;
    P2[idx] = (f2){c, A};
}

__global__ __launch_bounds__(256, 4) void score_kernel(
    const float* __restrict__ x, const float* __restrict__ t,
    const float* __restrict__ weights,
    const float* __restrict__ CA8, const f2* __restrict__ P2,
    float* __restrict__ out)
{
    const int b0  = blockIdx.x * G;
    const int tid = threadIdx.x;

    __shared__ __align__(16) float xT[Dc][G];   // x transposed
    __shared__ float part1[G][2][Kc];
    __shared__ float partL[G][2][Kc];
    __shared__ __align__(16) float peT[Kc][G];  // unnormalized softmax numerators
    __shared__ float wmax[G][2];
    __shared__ float wsum[G][2];

    // per-row scalars
    float e[G], na[G], sg[G];
    #pragma unroll
    for (int g = 0; g < G; ++g) {
        float tt = t[b0 + g];
        float Bt = fmaf(9.95f * tt, tt, 0.1f * tt);
        float ee = __expf(-Bt);
        e[g]  = ee;
        na[g] = -sqrtf(ee);
        sg[g] = sqrtf(1.0f - ee);
    }
    f2 e2[2]  = {{e[0], e[1]}, {e[2], e[3]}};
    f2 na2[2] = {{na[0], na[1]}, {na[2], na[3]}};

    #pragma unroll
    for (int g = 0; g < G; ++g)
        xT[tid][g] = x[(b0 + g) * Dc + tid];
    __syncthreads();

    // ---------------- pass 1: thread = (k, half-of-D) ----------------
    const int kk    = tid & (Kc - 1);
    const int half  = tid >> 7;
    const int dbase = half * (Dc / 2);           // 128 d's per thread

    const f4* xTv = (const f4*)(&xT[0][0]);
    const f2 one2 = {1.0f, 1.0f};

    f2 acc1[2] = {{0.f, 0.f}, {0.f, 0.f}};
    float accL[G] = {0.f, 0.f, 0.f, 0.f};

    for (int grp = 0; grp < 8; ++grp) {          // 16 d's per grp, 1 rcp/16d
        f2 Nacc[2], Dacc[2];
        #pragma unroll
        for (int q = 0; q < 4; ++q) {            // 4-d subquads
            const int d0 = dbase + grp * 16 + q * 4;
            const float* base = CA8 + ((size_t)(d0 >> 2) * Kc + kk) * 8;
            f4 c4 = *(const f4*)base;          // dwordx4, coalesced over kk
            f4 A4 = *(const f4*)(base + 4);    // same addr + imm 16
            f4 xv0 = xTv[d0 + 0];              // LDS b128 broadcast (d uniform)
            f4 xv1 = xTv[d0 + 1];
            f4 xv2 = xTv[d0 + 2];
            f4 xv3 = xTv[d0 + 3];
            #pragma unroll
            for (int p = 0; p < 2; ++p) {
                f2 ep = e2[p], nap = na2[p];
                f2 v0 = fma2(ep, splat2(A4[0]), one2);   // var in [0.25,1]
                f2 v1 = fma2(ep, splat2(A4[1]), one2);
                f2 v2 = fma2(ep, splat2(A4[2]), one2);
                f2 v3 = fma2(ep, splat2(A4[3]), one2);
                f2 f0 = fma2(nap, splat2(c4[0]), (f2){xv0[2*p], xv0[2*p+1]});
                f2 f1 = fma2(nap, splat2(c4[1]), (f2){xv1[2*p], xv1[2*p+1]});
                f2 f2_ = fma2(nap, splat2(c4[2]), (f2){xv2[2*p], xv2[2*p+1]});
                f2 f3 = fma2(nap, splat2(c4[3]), (f2){xv3[2*p], xv3[2*p+1]});
                f2 s0 = f0 * f0, s1 = f1 * f1, s2 = f2_ * f2_, s3 = f3 * f3;
                f2 d01 = v0 * v1, d23 = v2 * v3;
                f2 n01 = fma2(s1, v0, s0 * v1);
                f2 n23 = fma2(s3, v2, s2 * v3);
                f2 den4 = d01 * d23;
                f2 num4 = fma2(n23, d01, n01 * d23);
                if (q == 0) {                     // compile-time branch
                    Nacc[p] = num4;
                    Dacc[p] = den4;
                } else {                          // N' = N*d + n*D; D' = D*d
                    Nacc[p] = fma2(num4, Dacc[p], Nacc[p] * den4);
                    Dacc[p] = Dacc[p] * den4;
                }
            }
        }
        #pragma unroll
        for (int p = 0; p < 2; ++p) {
            f2 r = {__builtin_amdgcn_rcpf(Dacc[p][0]),
                    __builtin_amdgcn_rcpf(Dacc[p][1])};
            acc1[p] = fma2(Nacc[p], r, acc1[p]);
        }
        accL[0] += __log2f(Dacc[0][0]);        // Dacc = prod(var) over 16 d
        accL[1] += __log2f(Dacc[0][1]);
        accL[2] += __log2f(Dacc[1][0]);
        accL[3] += __log2f(Dacc[1][1]);
    }
    #pragma unroll
    for (int p = 0; p < 2; ++p) {
        part1[2*p  ][half][kk] = acc1[p][0];
        part1[2*p+1][half][kk] = acc1[p][1];
    }
    #pragma unroll
    for (int g = 0; g < G; ++g)
        partL[g][half][kk] = accL[g];
    __syncthreads();

    // ---------------- softmax over k (threads < K, 2 full waves) ----------------
    float lpv[G];
    if (tid < Kc) {
        float lw = __logf(weights[tid]);
        #pragma unroll
        for (int g = 0; g < G; ++g) {
            float S1 = part1[g][0][tid] + part1[g][1][tid];
            float S2 = partL[g][0][tid] + partL[g][1][tid];
            lpv[g] = fmaf(-0.5f, S1, fmaf(-88.72283911167299f, S2, lw)); // 128*ln2
            float m = lpv[g];
            #pragma unroll
            for (int off = 32; off > 0; off >>= 1)
                m = fmaxf(m, __shfl_xor(m, off, 64));
            if ((tid & 63) == 0) wmax[g][tid >> 6] = m;
        }
    }
    __syncthreads();
    if (tid < Kc) {
        #pragma unroll
        for (int g = 0; g < G; ++g) {
            float m  = fmaxf(wmax[g][0], wmax[g][1]);
            float pe = __expf(lpv[g] - m);
            peT[tid][g] = pe;                  // unnormalized; 1/Z in epilogue
            float s = pe;
            #pragma unroll
            for (int off = 32; off > 0; off >>= 1)
                s += __shfl_xor(s, off, 64);
            if ((tid & 63) == 0) wsum[g][tid >> 6] = s;
        }
    }
    __syncthreads();

    // ---------------- pass 2: thread = d, 1 rcp per 16 k's ----------------
    f4 xvv = xTv[tid];
    f2 xp[2] = {{xvv[0], xvv[1]}, {xvv[2], xvv[3]}};
    f2 O[2] = {{0.f, 0.f}, {0.f, 0.f}};
    const f4* peTv = (const f4*)(&peT[0][0]);
    const f2* pp = P2 + tid;

    for (int kt = 0; kt < 8; ++kt) {             // 16 k's per outer step
        f2 Nacc[2], Dacc[2];
        #pragma unroll
        for (int qq = 0; qq < 4; ++qq) {
            const int k0 = (kt * 4 + qq) * 4;
            f2 ca0 = pp[(k0 + 0) * Dc];        // dwordx2 {c,A}, coalesced
            f2 ca1 = pp[(k0 + 1) * Dc];
            f2 ca2 = pp[(k0 + 2) * Dc];
            f2 ca3 = pp[(k0 + 3) * Dc];
            f4 p0 = peTv[k0 + 0];              // LDS b128 broadcast
            f4 p1 = peTv[k0 + 1];
            f4 p2 = peTv[k0 + 2];
            f4 p3 = peTv[k0 + 3];
            #pragma unroll
            for (int p = 0; p < 2; ++p) {
                f2 ep = e2[p], nap = na2[p];
                f2 v0 = fma2(ep, splat2(ca0[1]), one2);
                f2 v1 = fma2(ep, splat2(ca1[1]), one2);
                f2 v2 = fma2(ep, splat2(ca2[1]), one2);
                f2 v3 = fma2(ep, splat2(ca3[1]), one2);
                f2 f0 = fma2(nap, splat2(ca0[0]), xp[p]);
                f2 f1 = fma2(nap, splat2(ca1[0]), xp[p]);
                f2 f2_ = fma2(nap, splat2(ca2[0]), xp[p]);
                f2 f3 = fma2(nap, splat2(ca3[0]), xp[p]);
                f2 u0 = (f2){p0[2*p], p0[2*p+1]} * f0;
                f2 u1 = (f2){p1[2*p], p1[2*p+1]} * f1;
                f2 u2 = (f2){p2[2*p], p2[2*p+1]} * f2_;
                f2 u3 = (f2){p3[2*p], p3[2*p+1]} * f3;
                f2 d01 = v0 * v1, d23 = v2 * v3;
                f2 n01 = fma2(u1, v0, u0 * v1);
                f2 n23 = fma2(u3, v2, u2 * v3);
                f2 den4 = d01 * d23;
                f2 num4 = fma2(n23, d01, n01 * d23);
                if (qq == 0) {
                    Nacc[p] = num4;
                    Dacc[p] = den4;
                } else {
                    Nacc[p] = fma2(num4, Dacc[p], Nacc[p] * den4);
                    Dacc[p] = Dacc[p] * den4;
                }
            }
        }
        #pragma unroll
        for (int p = 0; p < 2; ++p) {
            f2 r = {__builtin_amdgcn_rcpf(Dacc[p][0]),
                    __builtin_amdgcn_rcpf(Dacc[p][1])};
            O[p] = fma2(Nacc[p], r, O[p]);
        }
    }

    #pragma unroll
    for (int p = 0; p < 2; ++p) {
        #pragma unroll
        for (int j = 0; j < 2; ++j) {
            int g = 2 * p + j;
            float Z = wsum[g][0] + wsum[g][1];
            out[(b0 + g) * Dc + tid] = sg[g] * __builtin_amdgcn_rcpf(Z) * O[p][j];
        }
    }
}

extern "C" void kernel_launch(void* const* d_in, const int* in_sizes, int n_in,
                              void* d_out, int out_size, void* d_ws, size_t ws_size,
                              hipStream_t stream) {
    const float* x       = (const float*)d_in[0];
    const float* t       = (const float*)d_in[1];
    const float* centers = (const float*)d_in[2];
    const float* stds    = (const float*)d_in[3];
    const float* weights = (const float*)d_in[4];
    float* outp = (float*)d_out;

    float* CA8 = (float*)d_ws;                    // [D/4][K][8]  (256 KB)
    f2*    P2  = (f2*)(CA8 + Kc * Dc * 2);        // [K][D] {c,A} (256 KB)

    const int B = in_sizes[1];                    // 4096

    prep_kernel<<<(Kc * Dc + 255) / 256, 256, 0, stream>>>(centers, stds, CA8, P2);
    score_kernel<<<B / G, 256, 0, stream>>>(x, t, weights, CA8, P2, outp);
}

// Round 8
// 102.661 us; speedup vs baseline: 1.1296x; 1.0269x over previous
//
#include <hip/hip_runtime.h>
#include <math.h>

// B=4096, K=128, D=256.
// out[b,d] = sqrt(1-e) * sum_k p_k * (x - a*c)/var,  var = 1 + e*(s^2-1)
// lp_k = -0.5*S1 - 128*ln2*S2 + ln w_k  (k-uniform const dropped)
//   S1 = sum_d diff^2/var, S2 = sum_d log2(var)
//
// R0-R7 conclusions: VALU work is irreducible ~26us (rcp is quarter-rate =
// one pk-op; all division-combining depths are equivalent; R6/R7 regressed).
// Remaining gap model: per-CU TA address processing (~4 lanes/cy).  Pass 2's
// b64 loads (8B/lane) are the dominant TA consumer (2048 loads/CU x 16cy =
// 13.7us vs pass 1's 6.8).  R8 = verbatim R0 kernel + k-pair-interleaved
// pass-2 table: P4[(k/2)*Dc+d] = {c_k, A_k, c_k+1, A_k+1} -> b128 loads,
// pass-2 load count halves.  Math and op count bit-identical to R0.

constexpr int Kc = 128;
constexpr int Dc = 256;
constexpr int G  = 4;   // batch rows per block (2 f2 pairs)

typedef float f2 __attribute__((ext_vector_type(2)));
typedef float f4 __attribute__((ext_vector_type(4)));

static __device__ __forceinline__ f2 fma2(f2 a, f2 b, f2 c) {
    return __builtin_elementwise_fma(a, b, c);
}
static __device__ __forceinline__ f2 splat2(float s) { return (f2){s, s}; }

// prep: CA8[(d>>2)][k][8] = {c0,c1,c2,c3,A0,A1,A2,A3} (pass-1, transposed);
//       P4[(k>>1)*Dc + d] = {c_k, A_k, c_{k+1}, A_{k+1}} (pass-2), A = s^2-1.
__global__ void prep_kernel(const float* __restrict__ centers,
                            const float* __restrict__ stds,
                            float* __restrict__ CA8, float* __restrict__ P4) {
    int idx = blockIdx.x * blockDim.x + threadIdx.x;   // k*Dc + d, read-coalesced
    if (idx >= Kc * Dc) return;
    int k = idx >> 8;
    int d = idx & (Dc - 1);
    float c = centers[idx];
    float s = stds[idx];
    float A = s * s - 1.0f;
    int o = (d >> 2) * (Kc * 8) + k * 8 + (d & 3);
    CA8[o]     = c;
    CA8[o + 4] = A;
    int o4 = (((k >> 1) * Dc) + d) * 4 + (k & 1) * 2;
    P4[o4]     = c;
    P4[o4 + 1] = A;
}

__global__ __launch_bounds__(256, 6) void score_kernel(
    const float* __restrict__ x, const float* __restrict__ t,
    const float* __restrict__ weights,
    const float* __restrict__ CA8, const f4* __restrict__ P4,
    float* __restrict__ out)
{
    const int b0  = blockIdx.x * G;
    const int tid = threadIdx.x;

    __shared__ __align__(16) float xT[Dc][G];   // x transposed
    __shared__ float part1[G][2][Kc];
    __shared__ float partL[G][2][Kc];
    __shared__ __align__(16) float peT[Kc][G];  // unnormalized softmax numerators
    __shared__ float wmax[G][2];
    __shared__ float wsum[G][2];

    // per-row scalars
    float e[G], na[G], sg[G];
    #pragma unroll
    for (int g = 0; g < G; ++g) {
        float tt = t[b0 + g];
        float Bt = fmaf(9.95f * tt, tt, 0.1f * tt);
        float ee = __expf(-Bt);
        e[g]  = ee;
        na[g] = -sqrtf(ee);
        sg[g] = sqrtf(1.0f - ee);
    }
    f2 e2[2]  = {{e[0], e[1]}, {e[2], e[3]}};
    f2 na2[2] = {{na[0], na[1]}, {na[2], na[3]}};
    const f2 one2 = {1.0f, 1.0f};

    #pragma unroll
    for (int g = 0; g < G; ++g)
        xT[tid][g] = x[(b0 + g) * Dc + tid];
    __syncthreads();

    // ---------------- pass 1: thread = (k, half-of-D) ----------------
    const int kk    = tid & (Kc - 1);
    const int half  = tid >> 7;
    const int dbase = half * (Dc / 2);

    const f4* xTv = (const f4*)(&xT[0][0]);

    f2 acc1[2] = {{0.f, 0.f}, {0.f, 0.f}};
    float accL[G] = {0.f, 0.f, 0.f, 0.f};

    for (int grp = 0; grp < 8; ++grp) {
        f2 prod[2] = {{1.f, 1.f}, {1.f, 1.f}};
        #pragma unroll
        for (int q = 0; q < 4; ++q) {
            const int d0 = dbase + (grp * 4 + q) * 4;
            const float* base = CA8 + ((size_t)(d0 >> 2) * Kc + kk) * 8;
            f4 c4 = *(const f4*)base;          // dwordx4, coalesced over kk
            f4 A4 = *(const f4*)(base + 4);    // same addr + imm 16
            f4 xv0 = xTv[d0 + 0];              // LDS b128 broadcast (d uniform)
            f4 xv1 = xTv[d0 + 1];
            f4 xv2 = xTv[d0 + 2];
            f4 xv3 = xTv[d0 + 3];
            #pragma unroll
            for (int p = 0; p < 2; ++p) {
                f2 ep = e2[p], nap = na2[p];
                f2 x0 = {xv0[2*p], xv0[2*p+1]};
                f2 x1 = {xv1[2*p], xv1[2*p+1]};
                f2 x2 = {xv2[2*p], xv2[2*p+1]};
                f2 x3 = {xv3[2*p], xv3[2*p+1]};
                f2 v0 = fma2(ep, splat2(A4[0]), one2);   // var in [0.25,1]
                f2 v1 = fma2(ep, splat2(A4[1]), one2);
                f2 v2 = fma2(ep, splat2(A4[2]), one2);
                f2 v3 = fma2(ep, splat2(A4[3]), one2);
                f2 f0 = fma2(nap, splat2(c4[0]), x0);
                f2 f1 = fma2(nap, splat2(c4[1]), x1);
                f2 f2_ = fma2(nap, splat2(c4[2]), x2);
                f2 f3 = fma2(nap, splat2(c4[3]), x3);
                f2 s0 = f0 * f0, s1 = f1 * f1, s2 = f2_ * f2_, s3 = f3 * f3;
                f2 d01 = v0 * v1, d23 = v2 * v3;
                f2 n01 = fma2(s1, v0, s0 * v1);
                f2 n23 = fma2(s3, v2, s2 * v3);
                f2 den = d01 * d23;                      // >= 0.25^4
                f2 num = fma2(n23, d01, n01 * d23);
                f2 r = {__builtin_amdgcn_rcpf(den[0]),
                        __builtin_amdgcn_rcpf(den[1])};
                acc1[p] = fma2(num, r, acc1[p]);
                prod[p] = prod[p] * den;
            }
        }
        accL[0] += __log2f(prod[0][0]);        // 1 log per 16 d per g
        accL[1] += __log2f(prod[0][1]);
        accL[2] += __log2f(prod[1][0]);
        accL[3] += __log2f(prod[1][1]);
    }
    #pragma unroll
    for (int p = 0; p < 2; ++p) {
        part1[2*p  ][half][kk] = acc1[p][0];
        part1[2*p+1][half][kk] = acc1[p][1];
    }
    #pragma unroll
    for (int g = 0; g < G; ++g)
        partL[g][half][kk] = accL[g];
    __syncthreads();

    // ---------------- softmax over k (threads < K, 2 full waves) ----------------
    float lpv[G];
    if (tid < Kc) {
        float lw = __logf(weights[tid]);
        #pragma unroll
        for (int g = 0; g < G; ++g) {
            float S1 = part1[g][0][tid] + part1[g][1][tid];
            float S2 = partL[g][0][tid] + partL[g][1][tid];
            lpv[g] = fmaf(-0.5f, S1, fmaf(-88.72283911167299f, S2, lw)); // 128*ln2
            float m = lpv[g];
            #pragma unroll
            for (int off = 32; off > 0; off >>= 1)
                m = fmaxf(m, __shfl_xor(m, off, 64));
            if ((tid & 63) == 0) wmax[g][tid >> 6] = m;
        }
    }
    __syncthreads();
    if (tid < Kc) {
        #pragma unroll
        for (int g = 0; g < G; ++g) {
            float m  = fmaxf(wmax[g][0], wmax[g][1]);
            float pe = __expf(lpv[g] - m);
            peT[tid][g] = pe;                  // unnormalized; 1/Z in epilogue
            float s = pe;
            #pragma unroll
            for (int off = 32; off > 0; off >>= 1)
                s += __shfl_xor(s, off, 64);
            if ((tid & 63) == 0) wsum[g][tid >> 6] = s;
        }
    }
    __syncthreads();

    // ---------------- pass 2: thread = d, b128 k-pair table loads ----------------
    f4 xvv = xTv[tid];
    f2 xp[2] = {{xvv[0], xvv[1]}, {xvv[2], xvv[3]}};
    f2 O[2] = {{0.f, 0.f}, {0.f, 0.f}};
    const f4* peTv = (const f4*)(&peT[0][0]);
    const f4* pq = P4 + tid;                   // pq[(k/2)*Dc] = {c_k,A_k,c_k+1,A_k+1}

    for (int kq = 0; kq < 32; ++kq) {
        const int k0 = kq * 4;
        f4 q0 = pq[(k0 >> 1) * Dc];            // dwordx4: k0, k0+1
        f4 q1 = pq[((k0 >> 1) + 1) * Dc];      // dwordx4: k0+2, k0+3
        f4 p0 = peTv[k0 + 0];                  // LDS b128 broadcast
        f4 p1 = peTv[k0 + 1];
        f4 p2 = peTv[k0 + 2];
        f4 p3 = peTv[k0 + 3];
        #pragma unroll
        for (int p = 0; p < 2; ++p) {
            f2 ep = e2[p], nap = na2[p];
            f2 v0 = fma2(ep, splat2(q0[1]), one2);
            f2 v1 = fma2(ep, splat2(q0[3]), one2);
            f2 v2 = fma2(ep, splat2(q1[1]), one2);
            f2 v3 = fma2(ep, splat2(q1[3]), one2);
            f2 f0 = fma2(nap, splat2(q0[0]), xp[p]);
            f2 f1 = fma2(nap, splat2(q0[2]), xp[p]);
            f2 f2_ = fma2(nap, splat2(q1[0]), xp[p]);
            f2 f3 = fma2(nap, splat2(q1[2]), xp[p]);
            f2 u0 = (f2){p0[2*p], p0[2*p+1]} * f0;
            f2 u1 = (f2){p1[2*p], p1[2*p+1]} * f1;
            f2 u2 = (f2){p2[2*p], p2[2*p+1]} * f2_;
            f2 u3 = (f2){p3[2*p], p3[2*p+1]} * f3;
            f2 d01 = v0 * v1, d23 = v2 * v3;
            f2 n01 = fma2(u1, v0, u0 * v1);
            f2 n23 = fma2(u3, v2, u2 * v3);
            f2 den = d01 * d23;
            f2 num = fma2(n23, d01, n01 * d23);
            f2 r = {__builtin_amdgcn_rcpf(den[0]),
                    __builtin_amdgcn_rcpf(den[1])};
            O[p] = fma2(num, r, O[p]);
        }
    }

    #pragma unroll
    for (int p = 0; p < 2; ++p) {
        #pragma unroll
        for (int j = 0; j < 2; ++j) {
            int g = 2 * p + j;
            float Z = wsum[g][0] + wsum[g][1];
            out[(b0 + g) * Dc + tid] = sg[g] * __builtin_amdgcn_rcpf(Z) * O[p][j];
        }
    }
}

extern "C" void kernel_launch(void* const* d_in, const int* in_sizes, int n_in,
                              void* d_out, int out_size, void* d_ws, size_t ws_size,
                              hipStream_t stream) {
    const float* x       = (const float*)d_in[0];
    const float* t       = (const float*)d_in[1];
    const float* centers = (const float*)d_in[2];
    const float* stds    = (const float*)d_in[3];
    const float* weights = (const float*)d_in[4];
    float* outp = (float*)d_out;

    float* CA8 = (float*)d_ws;                    // [D/4][K][8]        (256 KB)
    float* P4  = CA8 + Kc * Dc * 2;               // [K/2][D]{c,A,c,A}  (256 KB)

    const int B = in_sizes[1];                    // 4096

    prep_kernel<<<(Kc * Dc + 255) / 256, 256, 0, stream>>>(centers, stds, CA8, P4);
    score_kernel<<<B / G, 256, 0, stream>>>(x, t, weights, CA8, (const f4*)P4, outp);
}